// Round 7
// baseline (675.518 us; speedup 1.0000x reference)
//
#include <hip/hip_runtime.h>
#include <stdint.h>

#define BATCH   512
#define NFEAT   128
#define ESIZE   2048   // encoded feature size (bits)
#define HSIZE   8192
#define NCLS    10
#define THRESH_I 4
#define CAP     128    // max sparse entries per row (mean ~32); > CAP => dense
#define ROWB    64     // bytes per bit-plane row (512 batches / 8)

// Bit-plane layout: actT[h] is 64 bytes; byte beta, bit i  <->  batch beta+64*i.
// Stripe = 1024 contiguous W elements. Masks: per stripe 64 dwords; lane L's
// dword covers elems {q*256 + L*4 + k}, bit pair 2*(q*4+k) = (nz, sign).

// ---------------------------------------------------------------------------
// Encode: one wave per feature f; lane beta handles batches beta+64i.
// Also zeroes outAcc and the pad row of each bit-plane buffer.
// ---------------------------------------------------------------------------
__global__ __launch_bounds__(256) void encode_kernel(
    const float* __restrict__ x,
    uint8_t* __restrict__ aT0, uint8_t* __restrict__ aT1,
    uint8_t* __restrict__ aT2, uint8_t* __restrict__ aT3,
    float* __restrict__ outAcc) {
  int t = blockIdx.x * 256 + threadIdx.x;        // 8192 threads
  if (t < BATCH * NCLS) outAcc[t] = 0.0f;
  else if (t < 5120 + 64)  aT0[(size_t)ESIZE * ROWB + (t - 5120)] = 0;
  else if (t < 5184 + 64)  aT1[(size_t)HSIZE * ROWB + (t - 5184)] = 0;
  else if (t < 5248 + 64)  aT2[(size_t)HSIZE * ROWB + (t - 5248)] = 0;
  else if (t < 5312 + 64)  aT3[(size_t)HSIZE * ROWB + (t - 5312)] = 0;

  int wave = threadIdx.x >> 6;
  int lane = threadIdx.x & 63;
  int f = blockIdx.x * 4 + wave;
  if (f < NFEAT) {
    float u[8];
#pragma unroll
    for (int i = 0; i < 8; ++i)
      u[i] = x[(size_t)(lane + 64 * i) * NFEAT + f] * 16.0f;
#pragma unroll
    for (int j = 0; j < 16; ++j) {
      uint32_t byte = 0;
#pragma unroll
      for (int i = 0; i < 8; ++i)
        byte |= (u[i] > (float)j ? 1u : 0u) << i;
      aT0[(size_t)(f * 16 + j) * ROWB + lane] = (uint8_t)byte;
    }
  }
}

// ---------------------------------------------------------------------------
// Pass A — scan: PURE streamer. One wave per 2 stripes (8 KB): 8 independent
// float4 loads, per-lane nz/sign packing (no ballots/atomics/scatter), two
// coalesced 256 B mask stores. Stripe space: W0 [0,16384), W1 [16384,81920),
// W2 [81920,147456).
// ---------------------------------------------------------------------------
__global__ __launch_bounds__(256, 8) void scan_kernel(
    const float* __restrict__ W0, const float* __restrict__ W1,
    const float* __restrict__ W2, uint32_t* __restrict__ masks) {
  int unit = (blockIdx.x * 256 + threadIdx.x) >> 6;  // 73728 units
  int lane = threadIdx.x & 63;
  int s0 = unit * 2;
  const float* W;
  size_t off;
  if (s0 < 16384)      { W = W0; off = (size_t)s0 * 1024; }
  else if (s0 < 81920) { W = W1; off = (size_t)(s0 - 16384) * 1024; }
  else                 { W = W2; off = (size_t)(s0 - 81920) * 1024; }
  const float4* w4 = (const float4*)(W + off);

  float4 c[8];
#pragma unroll
  for (int q = 0; q < 8; ++q) c[q] = w4[q * 64 + lane];

  uint32_t out0 = 0, out1 = 0;
#pragma unroll
  for (int q = 0; q < 8; ++q) {
    float v[4] = {c[q].x, c[q].y, c[q].z, c[q].w};
    uint32_t w = 0;
#pragma unroll
    for (int k = 0; k < 4; ++k) {
      uint32_t nz = (v[k] != 0.0f) ? 1u : 0u;
      uint32_t sg = (v[k] < 0.0f) ? 1u : 0u;
      w |= (nz | (sg << 1)) << (2 * ((q & 3) * 4 + k));
    }
    if (q < 4) out0 |= w; else out1 |= w;
  }
  masks[(size_t)s0 * 64 + lane] = out0;
  masks[(size_t)(s0 + 1) * 64 + lane] = out1;
}

// ---------------------------------------------------------------------------
// Pass B — compact: one wave per row. Lane reads its S mask dwords, local
// popcount, ONE wave prefix (__shfl_up), per-lane scatter of its ~0.5
// entries. Exact counts, zero atomics. Entry = (row_elem << 1) | sign.
// ---------------------------------------------------------------------------
template <int S>   // stripes per row: 2 (W0) or 8 (W1/W2)
__global__ __launch_bounds__(256, 8) void compact_kernel(
    const uint32_t* __restrict__ masks, int stripeBase, int widBase,
    uint32_t* __restrict__ lists, int* __restrict__ counts) {
  int wrow = (blockIdx.x * 256 + threadIdx.x) >> 6;  // row within this region
  int lane = threadIdx.x & 63;
  int wid = widBase + wrow;
  int sbase = stripeBase + wrow * S;

  uint32_t m[S];
  int cnt = 0;
#pragma unroll
  for (int j = 0; j < S; ++j) {
    m[j] = masks[(size_t)(sbase + j) * 64 + lane];
    cnt += (int)__popc(m[j] & 0x55555555u);
  }
  // inclusive wave prefix sum of cnt
  int pre = cnt;
#pragma unroll
  for (int d = 1; d < 64; d <<= 1) {
    int t = __shfl_up(pre, d);
    if (lane >= d) pre += t;
  }
  int pos = pre - cnt;                               // exclusive start
  uint32_t* lp = lists + (size_t)wid * CAP;
#pragma unroll
  for (int j = 0; j < S; ++j) {
    uint32_t nzm = m[j] & 0x55555555u;
    while (nzm) {
      int b = __builtin_ctz(nzm);
      nzm &= nzm - 1;
      int i = b >> 1;                                // elem-in-lane-dword
      int e = j * 1024 + ((i >> 2) << 8) + lane * 4 + (i & 3);
      uint32_t sign = (m[j] >> (b + 1)) & 1u;
      if (pos < CAP) lp[pos] = ((uint32_t)e << 1) | sign;
      ++pos;
    }
  }
  if (lane == 63) counts[wid] = pre;                 // total (exact)
}

// ---------------------------------------------------------------------------
// Sparse layer on bit-plane layout: per entry, lane loads ONE byte (the 8
// batches it owns). Tail group masked with sentinel e=P (zeroed pad row).
// ---------------------------------------------------------------------------
__device__ __forceinline__ void proc_ent(uint32_t ent,
                                         const uint8_t* __restrict__ aIn,
                                         int lane, int* z) {
  uint32_t negm = (uint32_t)(-(int)(ent & 1u));
  uint32_t ee = ent >> 1;
  uint32_t byte = (uint32_t)aIn[(size_t)ee * ROWB + lane];
#pragma unroll
  for (int i = 0; i < 8; ++i) {
    uint32_t t = (byte >> i) & 1u;
    z[i] += (int)((t ^ negm) - negm);
  }
}

__device__ __forceinline__ void proc_comp_dense(float v, int ebase,
                                                const uint8_t* __restrict__ aIn,
                                                int lane, int* z) {
  uint64_t m = __ballot(v != 0.0f);
  if (m == 0ull) return;
  uint64_t pm = __ballot(v > 0.0f);
  do {
    uint32_t src = (uint32_t)__builtin_ctzll(m);
    m &= m - 1;
    int e = ebase + 4 * (int)src;
    uint32_t negm = ((pm >> src) & 1ull) ? 0u : 0xFFFFFFFFu;
    uint32_t byte = (uint32_t)aIn[(size_t)e * ROWB + lane];
#pragma unroll
    for (int i = 0; i < 8; ++i) {
      uint32_t t = (byte >> i) & 1u;
      z[i] += (int)((t ^ negm) - negm);
    }
  } while (m);
}

template <int P>
__global__ __launch_bounds__(512, 4) void layer_kernel(
    const uint32_t* __restrict__ lists, const int* __restrict__ counts,
    const float* __restrict__ W,
    const uint8_t* __restrict__ aIn, uint8_t* __restrict__ aOut) {
  int wave = threadIdx.x >> 6;
  int lane = threadIdx.x & 63;
  int hbase = blockIdx.x * 16 + wave * 2;
  const uint32_t SENT = (uint32_t)(P << 1);

  for (int r = 0; r < 2; ++r) {
    int h = hbase + r;
    int z[8];
#pragma unroll
    for (int i = 0; i < 8; ++i) z[i] = 0;

    int cnt = counts[h];
    if (cnt <= CAP) {
      const uint32_t* lp = lists + (size_t)h * CAP;
      int full = cnt & ~7;
      for (int i = 0; i < full; i += 8) {
        uint4 eA = *(const uint4*)(lp + i);
        uint4 eB = *(const uint4*)(lp + i + 4);
        proc_ent(eA.x, aIn, lane, z);
        proc_ent(eA.y, aIn, lane, z);
        proc_ent(eA.z, aIn, lane, z);
        proc_ent(eA.w, aIn, lane, z);
        proc_ent(eB.x, aIn, lane, z);
        proc_ent(eB.y, aIn, lane, z);
        proc_ent(eB.z, aIn, lane, z);
        proc_ent(eB.w, aIn, lane, z);
      }
      if (cnt & 7) {
        uint4 eA = *(const uint4*)(lp + full);
        uint4 eB = *(const uint4*)(lp + full + 4);
        uint32_t ee[8] = {eA.x, eA.y, eA.z, eA.w, eB.x, eB.y, eB.z, eB.w};
#pragma unroll
        for (int j = 0; j < 8; ++j)
          ee[j] = (full + j < cnt) ? ee[j] : SENT;
#pragma unroll
        for (int j = 0; j < 8; ++j) proc_ent(ee[j], aIn, lane, z);
      }
    } else {
      // dense fallback (CAP overflow; effectively never taken)
      const float4* wrow = (const float4*)(W + (size_t)h * P) + lane;
      for (int it = 0; it < P / 256; ++it) {
        float4 wv = wrow[it * 64];
        int eb = it * 256;
        proc_comp_dense(wv.x, eb + 0, aIn, lane, z);
        proc_comp_dense(wv.y, eb + 1, aIn, lane, z);
        proc_comp_dense(wv.z, eb + 2, aIn, lane, z);
        proc_comp_dense(wv.w, eb + 3, aIn, lane, z);
      }
    }

    uint32_t ob = 0;
#pragma unroll
    for (int i = 0; i < 8; ++i)
      ob |= (z[i] >= THRESH_I ? 1u : 0u) << i;
    aOut[(size_t)h * ROWB + lane] = (uint8_t)ob;
  }
}

// ---------------------------------------------------------------------------
// Output accumulation on bit planes. Chunk of 128 rows per block; outConn
// chunk staged in LDS; per-thread acc[8][10]; LDS reduce then global atomics.
// ---------------------------------------------------------------------------
#define OCHUNK 128
__global__ __launch_bounds__(256, 4) void outacc_kernel(
    const float* __restrict__ outConn,
    const uint8_t* __restrict__ a1, const uint8_t* __restrict__ a2,
    const uint8_t* __restrict__ a3,
    float* __restrict__ outAcc) {
  __shared__ float shOC[OCHUNK][NCLS];
  __shared__ float shAcc[BATCH * NCLS];
  int tid = threadIdx.x;
  int gbase = blockIdx.x * OCHUNK;                 // 0..24448
  for (int idx = tid; idx < OCHUNK * NCLS; idx += 256)
    ((float*)shOC)[idx] = outConn[(size_t)gbase * NCLS + idx];
  for (int idx = tid; idx < BATCH * NCLS; idx += 256) shAcc[idx] = 0.0f;
  __syncthreads();

  int wave = tid >> 6;
  int lane = tid & 63;
  int layer = gbase >> 13;
  const uint8_t* aT = (layer == 0) ? a1 : (layer == 1) ? a2 : a3;
  int h0 = (gbase & (HSIZE - 1)) + wave * 32;

  float acc[8][NCLS];
#pragma unroll
  for (int i = 0; i < 8; ++i)
#pragma unroll
    for (int c = 0; c < NCLS; ++c) acc[i][c] = 0.0f;

  for (int r = 0; r < 32; ++r) {
    int row = h0 + r;
    uint32_t byte = (uint32_t)aT[(size_t)row * ROWB + lane];
    float bf[8];
#pragma unroll
    for (int i = 0; i < 8; ++i) bf[i] = (float)((byte >> i) & 1u);
    const float* oc = shOC[wave * 32 + r];
#pragma unroll
    for (int c = 0; c < NCLS; ++c) {
      float o = oc[c];
#pragma unroll
      for (int i = 0; i < 8; ++i) acc[i][c] += bf[i] * o;
    }
  }
#pragma unroll
  for (int i = 0; i < 8; ++i)
#pragma unroll
    for (int c = 0; c < NCLS; ++c)
      atomicAdd(&shAcc[(size_t)(lane + 64 * i) * NCLS + c], acc[i][c]);
  __syncthreads();
  for (int idx = tid; idx < BATCH * NCLS; idx += 256)
    atomicAdd(&outAcc[idx], shAcc[idx]);
}

// ---------------------------------------------------------------------------
// Final: argmax per batch; write preds (int32) then outAct (f32) into d_out.
// ---------------------------------------------------------------------------
__global__ __launch_bounds__(256) void final_kernel(
    const float* __restrict__ outAcc,
    int* __restrict__ preds,
    float* __restrict__ outF) {
  int b = blockIdx.x * 256 + threadIdx.x;
  if (b < BATCH) {
    float vals[NCLS];
#pragma unroll
    for (int c = 0; c < NCLS; ++c) vals[c] = outAcc[b * NCLS + c];
    float best = vals[0];
    int bi = 0;
#pragma unroll
    for (int c = 1; c < NCLS; ++c) {
      if (vals[c] > best) { best = vals[c]; bi = c; }
    }
    preds[b] = bi;
#pragma unroll
    for (int c = 0; c < NCLS; ++c) outF[b * NCLS + c] = vals[c];
  }
}

extern "C" void kernel_launch(void* const* d_in, const int* in_sizes, int n_in,
                              void* d_out, int out_size, void* d_ws, size_t ws_size,
                              hipStream_t stream) {
  const float* x       = (const float*)d_in[1];
  const float* W0      = (const float*)d_in[2];
  const float* W1      = (const float*)d_in[3];
  const float* W2      = (const float*)d_in[4];
  const float* outConn = (const float*)d_in[5];

  uint8_t* base = (uint8_t*)d_ws;
  uint8_t* aT0 = base;                               // (2048+1)*64 B
  uint8_t* aT1 = base + 0x40000;                     // (8192+1)*64 B each
  uint8_t* aT2 = aT1 + 0x90000;
  uint8_t* aT3 = aT2 + 0x90000;
  uint32_t* lists = (uint32_t*)(aT3 + 0x90000);      // 24576*CAP words (+slack)
  int* counts = (int*)((uint8_t*)lists +
                       ((size_t)3 * HSIZE * CAP + 64) * 4);
  float* outAcc = (float*)(counts + 3 * HSIZE);
  uint32_t* masks = (uint32_t*)((uint8_t*)outAcc + BATCH * NCLS * 4 + 256);
  // masks: 147456 stripes * 64 dwords = 37.75 MB

  encode_kernel<<<32, 256, 0, stream>>>(x, aT0, aT1, aT2, aT3, outAcc);
  // Pass A: 73728 units (2 stripes each) -> 18432 blocks of 256
  scan_kernel<<<18432, 256, 0, stream>>>(W0, W1, W2, masks);
  // Pass B: W0 rows (S=2), then W1+W2 rows (S=8)
  compact_kernel<2><<<2048, 256, 0, stream>>>(masks, 0, 0, lists, counts);
  compact_kernel<8><<<4096, 256, 0, stream>>>(masks, 16384, HSIZE, lists,
                                              counts);
  layer_kernel<ESIZE><<<512, 512, 0, stream>>>(
      lists, counts, W0, aT0, aT1);
  layer_kernel<HSIZE><<<512, 512, 0, stream>>>(
      lists + (size_t)HSIZE * CAP, counts + HSIZE, W1, aT1, aT2);
  layer_kernel<HSIZE><<<512, 512, 0, stream>>>(
      lists + (size_t)2 * HSIZE * CAP, counts + 2 * HSIZE, W2, aT2, aT3);
  outacc_kernel<<<192, 256, 0, stream>>>(outConn, aT1, aT2, aT3, outAcc);
  final_kernel<<<2, 256, 0, stream>>>(outAcc, (int*)d_out,
                                      (float*)d_out + BATCH);
}

// Round 9
// 627.955 us; speedup vs baseline: 1.0757x; 1.0757x over previous
//
#include <hip/hip_runtime.h>
#include <stdint.h>

#define BATCH   512
#define NFEAT   128
#define ESIZE   2048   // encoded feature size (bits)
#define HSIZE   8192
#define NCLS    10
#define THRESH_I 4
#define CAP     128    // max sparse entries per row (mean ~32); > CAP => dense
#define ROWB    64     // bytes per bit-plane row (512 batches / 8)

typedef float vf4 __attribute__((ext_vector_type(4)));  // nt-load-compatible

// Bit-plane layout: actT[h] is 64 bytes; byte beta, bit i  <->  batch beta+64*i.

// ---------------------------------------------------------------------------
// Encode: one wave per feature f; lane beta handles batches beta+64i.
// Produces actT0 rows e = f*16 + j. Also zeroes outAcc, the pad row of each
// bit-plane buffer (sentinel target), and the counts array for convert.
// ---------------------------------------------------------------------------
__global__ __launch_bounds__(256) void encode_kernel(
    const float* __restrict__ x,
    uint8_t* __restrict__ aT0, uint8_t* __restrict__ aT1,
    uint8_t* __restrict__ aT2, uint8_t* __restrict__ aT3,
    int* __restrict__ counts,
    float* __restrict__ outAcc) {
  int t = blockIdx.x * 256 + threadIdx.x;        // 8192 threads
  if (t < BATCH * NCLS) outAcc[t] = 0.0f;
  else if (t < 5120 + 64)  aT0[(size_t)ESIZE * ROWB + (t - 5120)] = 0;
  else if (t < 5184 + 64)  aT1[(size_t)HSIZE * ROWB + (t - 5184)] = 0;
  else if (t < 5248 + 64)  aT2[(size_t)HSIZE * ROWB + (t - 5248)] = 0;
  else if (t < 5312 + 64)  aT3[(size_t)HSIZE * ROWB + (t - 5312)] = 0;
  counts[t] = 0;
  counts[t + 8192] = 0;
  counts[t + 16384] = 0;

  int wave = threadIdx.x >> 6;
  int lane = threadIdx.x & 63;
  int f = blockIdx.x * 4 + wave;
  if (f < NFEAT) {
    float u[8];
#pragma unroll
    for (int i = 0; i < 8; ++i)
      u[i] = x[(size_t)(lane + 64 * i) * NFEAT + f] * 16.0f;
#pragma unroll
    for (int j = 0; j < 16; ++j) {
      uint32_t byte = 0;
#pragma unroll
      for (int i = 0; i < 8; ++i)
        byte |= (u[i] > (float)j ? 1u : 0u) << i;
      aT0[(size_t)(f * 16 + j) * ROWB + lane] = (uint8_t)byte;
    }
  }
}

// ---------------------------------------------------------------------------
// Convert (stripe-parallel, fused W0+W1+W2): one wave per 1024-element
// contiguous stripe-pair (never crosses a row). Four NON-TEMPORAL float4
// loads (bypass L1 allocation — the stream has zero reuse and the per-CU
// L1 line-concurrency pool is the suspected limiter), one wait, 16 ballots,
// ONE atomicAdd on counts[row] to reserve slots, scatter the few entries,
// exit. Entry = (elem_index << 1) | (w<0). counts end EXACT (no padding).
// ---------------------------------------------------------------------------
__global__ __launch_bounds__(256, 8) void convert_kernel(
    const float* __restrict__ W0, const float* __restrict__ W1,
    const float* __restrict__ W2,
    uint32_t* __restrict__ lists, int* __restrict__ counts) {
  int pair = (blockIdx.x * 256 + threadIdx.x) >> 6;  // global wave id
  int lane = threadIdx.x & 63;

  // region decode (wave-uniform): W0 = 16384 pairs, W1/W2 = 65536 each
  const float* W;
  int row, sloc, wid, P;
  if (pair < 16384) {
    W = W0; P = ESIZE;
    int s0 = pair * 2;
    row = s0 >> 2; sloc = s0 & 3; wid = row;
  } else if (pair < 16384 + 65536) {
    W = W1; P = HSIZE;
    int s0 = (pair - 16384) * 2;
    row = s0 >> 4; sloc = s0 & 15; wid = HSIZE + row;
  } else {
    W = W2; P = HSIZE;
    int s0 = (pair - 16384 - 65536) * 2;
    row = s0 >> 4; sloc = s0 & 15; wid = 2 * HSIZE + row;
  }

  const vf4* w4 = (const vf4*)(W + (size_t)row * P + (size_t)sloc * 512);
  vf4 c0 = __builtin_nontemporal_load(w4 + lane);
  vf4 c1 = __builtin_nontemporal_load(w4 + 64 + lane);
  vf4 c2 = __builtin_nontemporal_load(w4 + 128 + lane);
  vf4 c3 = __builtin_nontemporal_load(w4 + 192 + lane);

  float v[16] = {c0.x, c0.y, c0.z, c0.w, c1.x, c1.y, c1.z, c1.w,
                 c2.x, c2.y, c2.z, c2.w, c3.x, c3.y, c3.z, c3.w};
  uint64_t m[16];
  int tt[16];
#pragma unroll
  for (int k = 0; k < 16; ++k) {
    m[k] = __ballot(v[k] != 0.0f);
    tt[k] = (int)__popcll(m[k]);
  }
  int total = 0;
#pragma unroll
  for (int k = 0; k < 16; ++k) total += tt[k];
  if (total == 0) return;                            // wave-uniform early out

  int base = 0;
  if (lane == 0) base = atomicAdd(&counts[wid], total);
  base = __shfl(base, 0);

  uint64_t lmask = (lane == 0) ? 0ull : (~0ull >> (64 - lane));
  int ebase = sloc * 512;
  uint32_t* lp = lists + (size_t)wid * CAP;
  int off = base;
#pragma unroll
  for (int k = 0; k < 16; ++k) {
    if (v[k] != 0.0f) {
      int pos = off + (int)__popcll(m[k] & lmask);
      // elem = ebase + quarter*256 + 4*lane + (k&3)
      int e = ebase + (k >> 2) * 256 + (k & 3) + lane * 4;
      if (pos < CAP)
        lp[pos] = ((uint32_t)e << 1) | (v[k] < 0.0f ? 1u : 0u);
    }
    off += tt[k];
  }
}

// ---------------------------------------------------------------------------
// Sparse layer on bit-plane layout: per entry, lane loads ONE byte (the 8
// batches it owns) -> 64 B per wave per entry. Output = direct byte store.
// Tail group masked with sentinel e=P (zeroed pad row).
// ---------------------------------------------------------------------------
__device__ __forceinline__ void proc_ent(uint32_t ent,
                                         const uint8_t* __restrict__ aIn,
                                         int lane, int* z) {
  uint32_t negm = (uint32_t)(-(int)(ent & 1u));
  uint32_t ee = ent >> 1;
  uint32_t byte = (uint32_t)aIn[(size_t)ee * ROWB + lane];
#pragma unroll
  for (int i = 0; i < 8; ++i) {
    uint32_t t = (byte >> i) & 1u;
    z[i] += (int)((t ^ negm) - negm);
  }
}

__device__ __forceinline__ void proc_comp_dense(float v, int ebase,
                                                const uint8_t* __restrict__ aIn,
                                                int lane, int* z) {
  uint64_t m = __ballot(v != 0.0f);
  if (m == 0ull) return;
  uint64_t pm = __ballot(v > 0.0f);
  do {
    uint32_t src = (uint32_t)__builtin_ctzll(m);
    m &= m - 1;
    int e = ebase + 4 * (int)src;
    uint32_t negm = ((pm >> src) & 1ull) ? 0u : 0xFFFFFFFFu;
    uint32_t byte = (uint32_t)aIn[(size_t)e * ROWB + lane];
#pragma unroll
    for (int i = 0; i < 8; ++i) {
      uint32_t t = (byte >> i) & 1u;
      z[i] += (int)((t ^ negm) - negm);
    }
  } while (m);
}

template <int P>
__global__ __launch_bounds__(512, 4) void layer_kernel(
    const uint32_t* __restrict__ lists, const int* __restrict__ counts,
    const float* __restrict__ W,
    const uint8_t* __restrict__ aIn, uint8_t* __restrict__ aOut) {
  int wave = threadIdx.x >> 6;
  int lane = threadIdx.x & 63;
  int hbase = blockIdx.x * 16 + wave * 2;
  const uint32_t SENT = (uint32_t)(P << 1);

  for (int r = 0; r < 2; ++r) {
    int h = hbase + r;
    int z[8];
#pragma unroll
    for (int i = 0; i < 8; ++i) z[i] = 0;

    int cnt = counts[h];
    if (cnt <= CAP) {
      const uint32_t* lp = lists + (size_t)h * CAP;
      int full = cnt & ~7;
      for (int i = 0; i < full; i += 8) {
        uint4 eA = *(const uint4*)(lp + i);
        uint4 eB = *(const uint4*)(lp + i + 4);
        proc_ent(eA.x, aIn, lane, z);
        proc_ent(eA.y, aIn, lane, z);
        proc_ent(eA.z, aIn, lane, z);
        proc_ent(eA.w, aIn, lane, z);
        proc_ent(eB.x, aIn, lane, z);
        proc_ent(eB.y, aIn, lane, z);
        proc_ent(eB.z, aIn, lane, z);
        proc_ent(eB.w, aIn, lane, z);
      }
      if (cnt & 7) {
        // tail: load the 8-group (within CAP slack), mask beyond cnt
        uint4 eA = *(const uint4*)(lp + full);
        uint4 eB = *(const uint4*)(lp + full + 4);
        uint32_t ee[8] = {eA.x, eA.y, eA.z, eA.w, eB.x, eB.y, eB.z, eB.w};
#pragma unroll
        for (int j = 0; j < 8; ++j)
          ee[j] = (full + j < cnt) ? ee[j] : SENT;
#pragma unroll
        for (int j = 0; j < 8; ++j) proc_ent(ee[j], aIn, lane, z);
      }
    } else {
      // dense fallback (CAP overflow; effectively never taken)
      const float4* wrow = (const float4*)(W + (size_t)h * P) + lane;
      for (int it = 0; it < P / 256; ++it) {
        float4 wv = wrow[it * 64];
        int eb = it * 256;
        proc_comp_dense(wv.x, eb + 0, aIn, lane, z);
        proc_comp_dense(wv.y, eb + 1, aIn, lane, z);
        proc_comp_dense(wv.z, eb + 2, aIn, lane, z);
        proc_comp_dense(wv.w, eb + 3, aIn, lane, z);
      }
    }

    uint32_t ob = 0;
#pragma unroll
    for (int i = 0; i < 8; ++i)
      ob |= (z[i] >= THRESH_I ? 1u : 0u) << i;
    aOut[(size_t)h * ROWB + lane] = (uint8_t)ob;
  }
}

// ---------------------------------------------------------------------------
// Output accumulation on bit planes. Chunk of 128 rows per block; outConn
// chunk staged in LDS; per-thread acc[8][10]; LDS reduce then global atomics.
// ---------------------------------------------------------------------------
#define OCHUNK 128
__global__ __launch_bounds__(256, 4) void outacc_kernel(
    const float* __restrict__ outConn,
    const uint8_t* __restrict__ a1, const uint8_t* __restrict__ a2,
    const uint8_t* __restrict__ a3,
    float* __restrict__ outAcc) {
  __shared__ float shOC[OCHUNK][NCLS];
  __shared__ float shAcc[BATCH * NCLS];
  int tid = threadIdx.x;
  int gbase = blockIdx.x * OCHUNK;                 // 0..24448
  for (int idx = tid; idx < OCHUNK * NCLS; idx += 256)
    ((float*)shOC)[idx] = outConn[(size_t)gbase * NCLS + idx];
  for (int idx = tid; idx < BATCH * NCLS; idx += 256) shAcc[idx] = 0.0f;
  __syncthreads();

  int wave = tid >> 6;
  int lane = tid & 63;
  int layer = gbase >> 13;
  const uint8_t* aT = (layer == 0) ? a1 : (layer == 1) ? a2 : a3;
  int h0 = (gbase & (HSIZE - 1)) + wave * 32;

  float acc[8][NCLS];
#pragma unroll
  for (int i = 0; i < 8; ++i)
#pragma unroll
    for (int c = 0; c < NCLS; ++c) acc[i][c] = 0.0f;

  for (int r = 0; r < 32; ++r) {
    int row = h0 + r;
    uint32_t byte = (uint32_t)aT[(size_t)row * ROWB + lane];
    float bf[8];
#pragma unroll
    for (int i = 0; i < 8; ++i) bf[i] = (float)((byte >> i) & 1u);
    const float* oc = shOC[wave * 32 + r];
#pragma unroll
    for (int c = 0; c < NCLS; ++c) {
      float o = oc[c];
#pragma unroll
      for (int i = 0; i < 8; ++i) acc[i][c] += bf[i] * o;
    }
  }
#pragma unroll
  for (int i = 0; i < 8; ++i)
#pragma unroll
    for (int c = 0; c < NCLS; ++c)
      atomicAdd(&shAcc[(size_t)(lane + 64 * i) * NCLS + c], acc[i][c]);
  __syncthreads();
  for (int idx = tid; idx < BATCH * NCLS; idx += 256)
    atomicAdd(&outAcc[idx], shAcc[idx]);
}

// ---------------------------------------------------------------------------
// Final: argmax per batch; write preds (int32) then outAct (f32) into d_out.
// ---------------------------------------------------------------------------
__global__ __launch_bounds__(256) void final_kernel(
    const float* __restrict__ outAcc,
    int* __restrict__ preds,
    float* __restrict__ outF) {
  int b = blockIdx.x * 256 + threadIdx.x;
  if (b < BATCH) {
    float vals[NCLS];
#pragma unroll
    for (int c = 0; c < NCLS; ++c) vals[c] = outAcc[b * NCLS + c];
    float best = vals[0];
    int bi = 0;
#pragma unroll
    for (int c = 1; c < NCLS; ++c) {
      if (vals[c] > best) { best = vals[c]; bi = c; }
    }
    preds[b] = bi;
#pragma unroll
    for (int c = 0; c < NCLS; ++c) outF[b * NCLS + c] = vals[c];
  }
}

extern "C" void kernel_launch(void* const* d_in, const int* in_sizes, int n_in,
                              void* d_out, int out_size, void* d_ws, size_t ws_size,
                              hipStream_t stream) {
  const float* x       = (const float*)d_in[1];
  const float* W0      = (const float*)d_in[2];
  const float* W1      = (const float*)d_in[3];
  const float* W2      = (const float*)d_in[4];
  const float* outConn = (const float*)d_in[5];

  uint8_t* base = (uint8_t*)d_ws;
  uint8_t* aT0 = base;                               // (2048+1)*64 B
  uint8_t* aT1 = base + 0x40000;                     // (8192+1)*64 B each
  uint8_t* aT2 = aT1 + 0x90000;
  uint8_t* aT3 = aT2 + 0x90000;
  uint32_t* lists = (uint32_t*)(aT3 + 0x90000);      // 24576*CAP words (+slack)
  int* counts = (int*)((uint8_t*)lists +
                       ((size_t)3 * HSIZE * CAP + 64) * 4);
  float* outAcc = (float*)(counts + 3 * HSIZE);

  encode_kernel<<<32, 256, 0, stream>>>(x, aT0, aT1, aT2, aT3, counts, outAcc);
  // 147456 stripe-pairs -> 36864 blocks of 256 (4 waves/block)
  convert_kernel<<<36864, 256, 0, stream>>>(W0, W1, W2, lists, counts);
  layer_kernel<ESIZE><<<512, 512, 0, stream>>>(
      lists, counts, W0, aT0, aT1);
  layer_kernel<HSIZE><<<512, 512, 0, stream>>>(
      lists + (size_t)HSIZE * CAP, counts + HSIZE, W1, aT1, aT2);
  layer_kernel<HSIZE><<<512, 512, 0, stream>>>(
      lists + (size_t)2 * HSIZE * CAP, counts + 2 * HSIZE, W2, aT2, aT3);
  outacc_kernel<<<192, 256, 0, stream>>>(outConn, aT1, aT2, aT3, outAcc);
  final_kernel<<<2, 256, 0, stream>>>(outAcc, (int*)d_out,
                                      (float*)d_out + BATCH);
}

// Round 10
// 625.909 us; speedup vs baseline: 1.0793x; 1.0033x over previous
//
#include <hip/hip_runtime.h>
#include <stdint.h>

#define BATCH   512
#define NFEAT   128
#define ESIZE   2048   // encoded feature size (bits)
#define HSIZE   8192
#define NCLS    10
#define THRESH_I 4
#define CAP     128    // max sparse entries per row (mean ~32); > CAP => dense
#define ROWB    64     // bytes per bit-plane row (512 batches / 8)

typedef float vf4 __attribute__((ext_vector_type(4)));  // nt-load-compatible

// Bit-plane layout: actT[h] is 64 bytes; byte beta, bit i  <->  batch beta+64*i.

// ---------------------------------------------------------------------------
// Encode: one wave per feature f; lane beta handles batches beta+64i.
// Produces actT0 rows e = f*16 + j. Also zeroes outAcc, the pad row of each
// bit-plane buffer (sentinel target), and the counts array for convert.
// ---------------------------------------------------------------------------
__global__ __launch_bounds__(256) void encode_kernel(
    const float* __restrict__ x,
    uint8_t* __restrict__ aT0, uint8_t* __restrict__ aT1,
    uint8_t* __restrict__ aT2, uint8_t* __restrict__ aT3,
    int* __restrict__ counts,
    float* __restrict__ outAcc) {
  int t = blockIdx.x * 256 + threadIdx.x;        // 8192 threads
  if (t < BATCH * NCLS) outAcc[t] = 0.0f;
  else if (t < 5120 + 64)  aT0[(size_t)ESIZE * ROWB + (t - 5120)] = 0;
  else if (t < 5184 + 64)  aT1[(size_t)HSIZE * ROWB + (t - 5184)] = 0;
  else if (t < 5248 + 64)  aT2[(size_t)HSIZE * ROWB + (t - 5248)] = 0;
  else if (t < 5312 + 64)  aT3[(size_t)HSIZE * ROWB + (t - 5312)] = 0;
  counts[t] = 0;
  counts[t + 8192] = 0;
  counts[t + 16384] = 0;

  int wave = threadIdx.x >> 6;
  int lane = threadIdx.x & 63;
  int f = blockIdx.x * 4 + wave;
  if (f < NFEAT) {
    float u[8];
#pragma unroll
    for (int i = 0; i < 8; ++i)
      u[i] = x[(size_t)(lane + 64 * i) * NFEAT + f] * 16.0f;
#pragma unroll
    for (int j = 0; j < 16; ++j) {
      uint32_t byte = 0;
#pragma unroll
      for (int i = 0; i < 8; ++i)
        byte |= (u[i] > (float)j ? 1u : 0u) << i;
      aT0[(size_t)(f * 16 + j) * ROWB + lane] = (uint8_t)byte;
    }
  }
}

// ---------------------------------------------------------------------------
// Convert (unit-parallel, fused W0+W1+W2): one wave per 2048-element aligned
// unit (8 KB, always within ONE row). Eight NON-TEMPORAL dwordx4 loads in
// flight (L1 bypass — validated round 9), then two 1024-elem groups, each:
// 16 ballots (SGPR-resident masks), one atomicAdd slot reservation, sparse
// scatter. Entry = (row_elem << 1) | (w<0). counts end EXACT.
// ---------------------------------------------------------------------------
__device__ __forceinline__ void cvt_group(
    const vf4* c, int gbase, int ebase, int wid, int lane, uint64_t lmask,
    uint32_t* __restrict__ lists, int* __restrict__ counts) {
  float v[16] = {c[0].x, c[0].y, c[0].z, c[0].w, c[1].x, c[1].y, c[1].z,
                 c[1].w, c[2].x, c[2].y, c[2].z, c[2].w, c[3].x, c[3].y,
                 c[3].z, c[3].w};
  uint64_t m[16];
  int tt[16];
#pragma unroll
  for (int k = 0; k < 16; ++k) {
    m[k] = __ballot(v[k] != 0.0f);
    tt[k] = (int)__popcll(m[k]);
  }
  int total = 0;
#pragma unroll
  for (int k = 0; k < 16; ++k) total += tt[k];
  if (total == 0) return;                            // wave-uniform

  int base = 0;
  if (lane == 0) base = atomicAdd(&counts[wid], total);
  base = __shfl(base, 0);

  uint32_t* lp = lists + (size_t)wid * CAP;
  int off = base;
#pragma unroll
  for (int k = 0; k < 16; ++k) {
    if (v[k] != 0.0f) {
      int pos = off + (int)__popcll(m[k] & lmask);
      int e = ebase + gbase + (k >> 2) * 256 + (k & 3) + lane * 4;
      if (pos < CAP)
        lp[pos] = ((uint32_t)e << 1) | (v[k] < 0.0f ? 1u : 0u);
    }
    off += tt[k];
  }
}

__global__ __launch_bounds__(256, 8) void convert_kernel(
    const float* __restrict__ W0, const float* __restrict__ W1,
    const float* __restrict__ W2,
    uint32_t* __restrict__ lists, int* __restrict__ counts) {
  int unit = (blockIdx.x * 256 + threadIdx.x) >> 6;  // 73728 units
  int lane = threadIdx.x & 63;

  // region decode (wave-uniform): W0 = 8192 units (1/row), W1/W2 = 32768
  const float* W;
  int row, ebase, wid, P;
  if (unit < 8192) {
    W = W0; P = ESIZE; row = unit; ebase = 0; wid = unit;
  } else if (unit < 8192 + 32768) {
    W = W1; P = HSIZE;
    int q = unit - 8192;
    row = q >> 2; ebase = (q & 3) * 2048; wid = HSIZE + row;
  } else {
    W = W2; P = HSIZE;
    int q = unit - 8192 - 32768;
    row = q >> 2; ebase = (q & 3) * 2048; wid = 2 * HSIZE + row;
  }

  const vf4* w4 = (const vf4*)(W + (size_t)row * P + (size_t)ebase);
  vf4 c[8];
#pragma unroll
  for (int j = 0; j < 8; ++j)
    c[j] = __builtin_nontemporal_load(w4 + j * 64 + lane);

  uint64_t lmask = (lane == 0) ? 0ull : (~0ull >> (64 - lane));
  cvt_group(c,     0,    ebase, wid, lane, lmask, lists, counts);
  cvt_group(c + 4, 1024, ebase, wid, lane, lmask, lists, counts);
}

// ---------------------------------------------------------------------------
// Sparse layer on bit-plane layout: per entry, lane loads ONE byte (the 8
// batches it owns) -> 64 B per wave per entry. Output = direct byte store.
// Tail group masked with sentinel e=P (zeroed pad row).
// ---------------------------------------------------------------------------
__device__ __forceinline__ void proc_ent(uint32_t ent,
                                         const uint8_t* __restrict__ aIn,
                                         int lane, int* z) {
  uint32_t negm = (uint32_t)(-(int)(ent & 1u));
  uint32_t ee = ent >> 1;
  uint32_t byte = (uint32_t)aIn[(size_t)ee * ROWB + lane];
#pragma unroll
  for (int i = 0; i < 8; ++i) {
    uint32_t t = (byte >> i) & 1u;
    z[i] += (int)((t ^ negm) - negm);
  }
}

__device__ __forceinline__ void proc_comp_dense(float v, int ebase,
                                                const uint8_t* __restrict__ aIn,
                                                int lane, int* z) {
  uint64_t m = __ballot(v != 0.0f);
  if (m == 0ull) return;
  uint64_t pm = __ballot(v > 0.0f);
  do {
    uint32_t src = (uint32_t)__builtin_ctzll(m);
    m &= m - 1;
    int e = ebase + 4 * (int)src;
    uint32_t negm = ((pm >> src) & 1ull) ? 0u : 0xFFFFFFFFu;
    uint32_t byte = (uint32_t)aIn[(size_t)e * ROWB + lane];
#pragma unroll
    for (int i = 0; i < 8; ++i) {
      uint32_t t = (byte >> i) & 1u;
      z[i] += (int)((t ^ negm) - negm);
    }
  } while (m);
}

template <int P>
__global__ __launch_bounds__(512, 4) void layer_kernel(
    const uint32_t* __restrict__ lists, const int* __restrict__ counts,
    const float* __restrict__ W,
    const uint8_t* __restrict__ aIn, uint8_t* __restrict__ aOut) {
  int wave = threadIdx.x >> 6;
  int lane = threadIdx.x & 63;
  int hbase = blockIdx.x * 16 + wave * 2;
  const uint32_t SENT = (uint32_t)(P << 1);

  for (int r = 0; r < 2; ++r) {
    int h = hbase + r;
    int z[8];
#pragma unroll
    for (int i = 0; i < 8; ++i) z[i] = 0;

    int cnt = counts[h];
    if (cnt <= CAP) {
      const uint32_t* lp = lists + (size_t)h * CAP;
      int full = cnt & ~7;
      for (int i = 0; i < full; i += 8) {
        uint4 eA = *(const uint4*)(lp + i);
        uint4 eB = *(const uint4*)(lp + i + 4);
        proc_ent(eA.x, aIn, lane, z);
        proc_ent(eA.y, aIn, lane, z);
        proc_ent(eA.z, aIn, lane, z);
        proc_ent(eA.w, aIn, lane, z);
        proc_ent(eB.x, aIn, lane, z);
        proc_ent(eB.y, aIn, lane, z);
        proc_ent(eB.z, aIn, lane, z);
        proc_ent(eB.w, aIn, lane, z);
      }
      if (cnt & 7) {
        // tail: load the 8-group (within CAP slack), mask beyond cnt
        uint4 eA = *(const uint4*)(lp + full);
        uint4 eB = *(const uint4*)(lp + full + 4);
        uint32_t ee[8] = {eA.x, eA.y, eA.z, eA.w, eB.x, eB.y, eB.z, eB.w};
#pragma unroll
        for (int j = 0; j < 8; ++j)
          ee[j] = (full + j < cnt) ? ee[j] : SENT;
#pragma unroll
        for (int j = 0; j < 8; ++j) proc_ent(ee[j], aIn, lane, z);
      }
    } else {
      // dense fallback (CAP overflow; effectively never taken)
      const float4* wrow = (const float4*)(W + (size_t)h * P) + lane;
      for (int it = 0; it < P / 256; ++it) {
        float4 wv = wrow[it * 64];
        int eb = it * 256;
        proc_comp_dense(wv.x, eb + 0, aIn, lane, z);
        proc_comp_dense(wv.y, eb + 1, aIn, lane, z);
        proc_comp_dense(wv.z, eb + 2, aIn, lane, z);
        proc_comp_dense(wv.w, eb + 3, aIn, lane, z);
      }
    }

    uint32_t ob = 0;
#pragma unroll
    for (int i = 0; i < 8; ++i)
      ob |= (z[i] >= THRESH_I ? 1u : 0u) << i;
    aOut[(size_t)h * ROWB + lane] = (uint8_t)ob;
  }
}

// ---------------------------------------------------------------------------
// Output accumulation on bit planes. Chunk of 128 rows per block; outConn
// chunk staged in LDS; per-thread acc[8][10]; LDS reduce then global atomics.
// ---------------------------------------------------------------------------
#define OCHUNK 128
__global__ __launch_bounds__(256, 4) void outacc_kernel(
    const float* __restrict__ outConn,
    const uint8_t* __restrict__ a1, const uint8_t* __restrict__ a2,
    const uint8_t* __restrict__ a3,
    float* __restrict__ outAcc) {
  __shared__ float shOC[OCHUNK][NCLS];
  __shared__ float shAcc[BATCH * NCLS];
  int tid = threadIdx.x;
  int gbase = blockIdx.x * OCHUNK;                 // 0..24448
  for (int idx = tid; idx < OCHUNK * NCLS; idx += 256)
    ((float*)shOC)[idx] = outConn[(size_t)gbase * NCLS + idx];
  for (int idx = tid; idx < BATCH * NCLS; idx += 256) shAcc[idx] = 0.0f;
  __syncthreads();

  int wave = tid >> 6;
  int lane = tid & 63;
  int layer = gbase >> 13;
  const uint8_t* aT = (layer == 0) ? a1 : (layer == 1) ? a2 : a3;
  int h0 = (gbase & (HSIZE - 1)) + wave * 32;

  float acc[8][NCLS];
#pragma unroll
  for (int i = 0; i < 8; ++i)
#pragma unroll
    for (int c = 0; c < NCLS; ++c) acc[i][c] = 0.0f;

  for (int r = 0; r < 32; ++r) {
    int row = h0 + r;
    uint32_t byte = (uint32_t)aT[(size_t)row * ROWB + lane];
    float bf[8];
#pragma unroll
    for (int i = 0; i < 8; ++i) bf[i] = (float)((byte >> i) & 1u);
    const float* oc = shOC[wave * 32 + r];
#pragma unroll
    for (int c = 0; c < NCLS; ++c) {
      float o = oc[c];
#pragma unroll
      for (int i = 0; i < 8; ++i) acc[i][c] += bf[i] * o;
    }
  }
#pragma unroll
  for (int i = 0; i < 8; ++i)
#pragma unroll
    for (int c = 0; c < NCLS; ++c)
      atomicAdd(&shAcc[(size_t)(lane + 64 * i) * NCLS + c], acc[i][c]);
  __syncthreads();
  for (int idx = tid; idx < BATCH * NCLS; idx += 256)
    atomicAdd(&outAcc[idx], shAcc[idx]);
}

// ---------------------------------------------------------------------------
// Final: argmax per batch; write preds (int32) then outAct (f32) into d_out.
// ---------------------------------------------------------------------------
__global__ __launch_bounds__(256) void final_kernel(
    const float* __restrict__ outAcc,
    int* __restrict__ preds,
    float* __restrict__ outF) {
  int b = blockIdx.x * 256 + threadIdx.x;
  if (b < BATCH) {
    float vals[NCLS];
#pragma unroll
    for (int c = 0; c < NCLS; ++c) vals[c] = outAcc[b * NCLS + c];
    float best = vals[0];
    int bi = 0;
#pragma unroll
    for (int c = 1; c < NCLS; ++c) {
      if (vals[c] > best) { best = vals[c]; bi = c; }
    }
    preds[b] = bi;
#pragma unroll
    for (int c = 0; c < NCLS; ++c) outF[b * NCLS + c] = vals[c];
  }
}

extern "C" void kernel_launch(void* const* d_in, const int* in_sizes, int n_in,
                              void* d_out, int out_size, void* d_ws, size_t ws_size,
                              hipStream_t stream) {
  const float* x       = (const float*)d_in[1];
  const float* W0      = (const float*)d_in[2];
  const float* W1      = (const float*)d_in[3];
  const float* W2      = (const float*)d_in[4];
  const float* outConn = (const float*)d_in[5];

  uint8_t* base = (uint8_t*)d_ws;
  uint8_t* aT0 = base;                               // (2048+1)*64 B
  uint8_t* aT1 = base + 0x40000;                     // (8192+1)*64 B each
  uint8_t* aT2 = aT1 + 0x90000;
  uint8_t* aT3 = aT2 + 0x90000;
  uint32_t* lists = (uint32_t*)(aT3 + 0x90000);      // 24576*CAP words (+slack)
  int* counts = (int*)((uint8_t*)lists +
                       ((size_t)3 * HSIZE * CAP + 64) * 4);
  float* outAcc = (float*)(counts + 3 * HSIZE);

  encode_kernel<<<32, 256, 0, stream>>>(x, aT0, aT1, aT2, aT3, counts, outAcc);
  // 73728 units (2048 elems each) -> 18432 blocks of 256 (4 waves/block)
  convert_kernel<<<18432, 256, 0, stream>>>(W0, W1, W2, lists, counts);
  layer_kernel<ESIZE><<<512, 512, 0, stream>>>(
      lists, counts, W0, aT0, aT1);
  layer_kernel<HSIZE><<<512, 512, 0, stream>>>(
      lists + (size_t)HSIZE * CAP, counts + HSIZE, W1, aT1, aT2);
  layer_kernel<HSIZE><<<512, 512, 0, stream>>>(
      lists + (size_t)2 * HSIZE * CAP, counts + 2 * HSIZE, W2, aT2, aT3);
  outacc_kernel<<<192, 256, 0, stream>>>(outConn, aT1, aT2, aT3, outAcc);
  final_kernel<<<2, 256, 0, stream>>>(outAcc, (int*)d_out,
                                      (float*)d_out + BATCH);
}